// Round 12
// baseline (1527.118 us; speedup 1.0000x reference)
//
#include <hip/hip_runtime.h>
#include <math.h>

#define NNODES 5000
#define NEDGES 80000
#define NB 8
#define NIN 30
#define K0PAD 32
#define NH 4
#define ND 64
#define NHD 256
#define NT 5
#define NOUT 3
#define ROWS (NB * NNODES) // 40000
#define BNEPS 1e-5f
#define KP 40   // LDS k-stride for A tile (shorts); 80B rows -> 2-way alias (free)
#define NREP 64 // sums[] replicas (attn-fused BN: 10000 blocks / 64 = 156 per addr)
#define BM 32   // gemm M-tile (32 -> 1250 blocks, 4.9/CU co-residency)

#define GLOBAL_AS __attribute__((address_space(1)))
#define LDS_AS __attribute__((address_space(3)))

typedef short shortx8 __attribute__((ext_vector_type(8)));
typedef _Float16 halfx8 __attribute__((ext_vector_type(8)));
typedef _Float16 halfx4 __attribute__((ext_vector_type(4)));
typedef _Float16 halfx2 __attribute__((ext_vector_type(2)));
typedef float floatx4 __attribute__((ext_vector_type(4)));

static __device__ __forceinline__ unsigned short f2h(float f) {
    union { _Float16 h; unsigned short u; } v;
    v.h = (_Float16)f;
    return v.u;
}
static __device__ __forceinline__ float h2f(unsigned short u) {
    union { _Float16 h; unsigned short u; } v;
    v.u = u;
    return (float)v.h;
}

// ---------------- CSR build ----------------

__global__ void count_kernel(const int* __restrict__ dst, int* __restrict__ counts, int n) {
    int e = blockIdx.x * blockDim.x + threadIdx.x;
    if (e < n) atomicAdd(&counts[dst[e]], 1);
}

__global__ __launch_bounds__(1024) void scan_kernel(const int* __restrict__ counts,
                                                    int* __restrict__ offsets, int n) {
    __shared__ int smem[1024];
    const int CH = 5;
    int tid = threadIdx.x;
    int base = tid * CH;
    int loc[CH];
    int s = 0;
    for (int j = 0; j < CH; ++j) {
        int i = base + j;
        int v = (i < n) ? counts[i] : 0;
        loc[j] = s;
        s += v;
    }
    smem[tid] = s;
    __syncthreads();
    for (int off = 1; off < 1024; off <<= 1) {
        int v = (tid >= off) ? smem[tid - off] : 0;
        __syncthreads();
        smem[tid] += v;
        __syncthreads();
    }
    int excl = smem[tid] - s;
    for (int j = 0; j < CH; ++j) {
        int i = base + j;
        if (i < n) offsets[i] = excl + loc[j];
    }
    if (tid == 1023) offsets[n] = smem[1023];
}

__global__ void fill_kernel(const int* __restrict__ src, const int* __restrict__ dst,
                            const int* __restrict__ offsets, int* __restrict__ cursor,
                            int* __restrict__ csr_src, int n) {
    int e = blockIdx.x * blockDim.x + threadIdx.x;
    if (e >= n) return;
    int d = dst[e];
    int pos = offsets[d] + atomicAdd(&cursor[d], 1);
    csr_src[pos] = src[e];
}

// ---------------- packing ----------------

__global__ void pack_xx_kernel(const float* __restrict__ xx, unsigned short* __restrict__ xx16) {
    int idx = blockIdx.x * blockDim.x + threadIdx.x;
    if (idx >= ROWS * K0PAD) return;
    int g = idx >> 5;
    int k = idx & 31;
    float v = (k < NIN) ? xx[(size_t)g * NIN + k] : 0.0f;
    xx16[idx] = f2h(v);
}

// WtP: per 32-k tile, 16B chunks (n,quad) at swizzled pos p = n*4 + (quad ^ ((n>>1)&3)).
__global__ void packWt_kernel(const float* __restrict__ W0, const float* __restrict__ W1,
                              const float* __restrict__ W2, const float* __restrict__ W3,
                              unsigned short* __restrict__ P0, unsigned short* __restrict__ P1,
                              unsigned short* __restrict__ P2, unsigned short* __restrict__ P3) {
    int l = blockIdx.y;
    const float* W = (l == 0) ? W0 : (l == 1) ? W1 : (l == 2) ? W2 : W3;
    unsigned short* WtP = (l == 0) ? P0 : (l == 1) ? P1 : (l == 2) ? P2 : P3;
    int Kin = (l == 0) ? NIN : NHD;
    int Kpad = (l == 0) ? K0PAD : NHD;
    int n = blockIdx.x;
    int k = threadIdx.x;
    if (k < Kpad) {
        float v = (k < Kin) ? W[(size_t)k * NHD + n] : 0.0f;
        int t = k >> 5;
        int quad = (k >> 3) & 3;
        int j = k & 7;
        int p = n * 4 + (quad ^ ((n >> 1) & 3));
        WtP[(size_t)t * (NHD * 32) + p * 8 + j] = f2h(v);
    }
}

// ---------------- MFMA GEMM + fused BN(prev layer) on A + fused el/er ----------------
// Reads BN stats from sums_read (filled by previous attn); zeroes sums_zero
// (the buffer the NEXT attn in stream order will fill) across first 128 blocks.

__global__ __launch_bounds__(256) void gemm_mfma_kernel(
    const unsigned short* __restrict__ A, const unsigned short* __restrict__ Wt,
    const float* __restrict__ alw, const float* __restrict__ arw,
    const float* __restrict__ sums_read, float* __restrict__ sums_zero,
    const float* __restrict__ gamma, const float* __restrict__ beta, int apply_bn,
    unsigned short* __restrict__ C16, float* __restrict__ el, float* __restrict__ er,
    int K) {
    __shared__ __align__(16) short As[BM * KP];
    __shared__ __align__(16) short Bs[256 * 32];
    __shared__ float bn_scale[NHD];
    __shared__ float bn_shift[NHD];
    int tid = threadIdx.x;
    // zero the other sums buffer for the upcoming attn (stream order guarantees safety)
    {
        int zi = blockIdx.x * 256 + tid;
        if (zi < NREP * 2 * NHD) sums_zero[zi] = 0.0f;
    }
    if (apply_bn) {
        int c = tid;
        float s = 0.0f, s2 = 0.0f;
        for (int r2 = 0; r2 < NREP; ++r2) {
            s += sums_read[r2 * 2 * NHD + c];
            s2 += sums_read[r2 * 2 * NHD + NHD + c];
        }
        const float invn = 1.0f / (float)ROWS;
        float mu = s * invn;
        float var = s2 * invn - mu * mu;
        float sc = rsqrtf(var + BNEPS) * gamma[c];
        bn_scale[c] = sc;
        bn_shift[c] = beta[c] - mu * sc;
    }
    __syncthreads();

    int wave = tid >> 6; // head
    int lane = tid & 63;
    int c = lane & 15;
    int quad = lane >> 4;
    int xorv = (c >> 1) & 3;
    int row0 = blockIdx.x * BM;

    floatx4 acc[2][4];
#pragma unroll
    for (int mt = 0; mt < 2; ++mt)
#pragma unroll
        for (int nt = 0; nt < 4; ++nt) acc[mt][nt] = (floatx4){0.f, 0.f, 0.f, 0.f};

    int r = tid >> 2;   // 0..63 (only <BM used)
    int seg = tid & 3;
    for (int k0 = 0; k0 < K; k0 += 32) {
        const unsigned short* gB = Wt + (size_t)(k0 >> 5) * (NHD * 32);
#pragma unroll
        for (int i = 0; i < 4; ++i) {
            int ci = i * 256 + tid;
            __builtin_amdgcn_global_load_lds(
                (const GLOBAL_AS unsigned int*)(gB + ci * 8),
                (LDS_AS unsigned int*)(&Bs[ci * 8]), 16, 0, 0);
        }
        if (r < BM) {
            shortx8 v = *(const shortx8*)(A + (size_t)(row0 + r) * K + k0 + seg * 8);
            if (apply_bn) {
                halfx8 hv = *(halfx8*)&v;
                int kg = k0 + seg * 8;
#pragma unroll
                for (int j = 0; j < 8; ++j) {
                    float x = (float)hv[j];
                    x = fmaf(x, bn_scale[kg + j], bn_shift[kg + j]);
                    x = (x > 0.0f) ? x : 0.01f * x;
                    hv[j] = (_Float16)x;
                }
                v = *(shortx8*)&hv;
            }
            *(shortx8*)(&As[r * KP + seg * 8]) = v;
        }
        __syncthreads();
        halfx8 a[2], b[4];
#pragma unroll
        for (int mt = 0; mt < 2; ++mt)
            a[mt] = *(const halfx8*)(&As[(mt * 16 + c) * KP + quad * 8]);
#pragma unroll
        for (int nt = 0; nt < 4; ++nt) {
            int pq = (wave * 64 + nt * 16 + c) * 4 + (quad ^ xorv);
            b[nt] = *(const halfx8*)(&Bs[pq * 8]);
        }
#pragma unroll
        for (int mt = 0; mt < 2; ++mt)
#pragma unroll
            for (int nt = 0; nt < 4; ++nt)
                acc[mt][nt] = __builtin_amdgcn_mfma_f32_16x16x32_f16(a[mt], b[nt],
                                                                     acc[mt][nt], 0, 0, 0);
        __syncthreads();
    }

    float alv[4], arv[4];
#pragma unroll
    for (int nt = 0; nt < 4; ++nt) {
        alv[nt] = alw[wave * 64 + nt * 16 + c];
        arv[nt] = arw[wave * 64 + nt * 16 + c];
    }
#pragma unroll
    for (int mt = 0; mt < 2; ++mt) {
#pragma unroll
        for (int rr = 0; rr < 4; ++rr) {
            int row = row0 + mt * 16 + quad * 4 + rr;
            float pl = 0.0f, pr = 0.0f;
#pragma unroll
            for (int nt = 0; nt < 4; ++nt) {
                float v = acc[mt][nt][rr];
                C16[(size_t)row * NHD + wave * 64 + nt * 16 + c] = f2h(v);
                pl += v * alv[nt];
                pr += v * arv[nt];
            }
#pragma unroll
            for (int o = 1; o < 16; o <<= 1) {
                pl += __shfl_xor(pl, o);
                pr += __shfl_xor(pr, o);
            }
            if (c == mt * 4 + rr) {
                el[(size_t)row * NH + wave] = pl;
                er[(size_t)row * NH + wave] = pr;
            }
        }
    }
}

// ---------------- edge softmax + aggregate + FUSED BN partial reduce ----------------
// Wave per node. Phase 1 logits once per node; phase 2 coalesced halfx8 gather.
// Epilogue: each wave writes its node's 256 (val, val^2) into a private LDS
// slice (full coverage per wave in every path), one barrier, 256-thread
// cross-wave reduce, 2 global atomics/thread into replica blk&63.

__global__ __launch_bounds__(256) void attn_kernel(const unsigned short* __restrict__ h16,
                                                   const float* __restrict__ el,
                                                   const float* __restrict__ er,
                                                   const int* __restrict__ offsets,
                                                   const int* __restrict__ csr_src,
                                                   unsigned short* __restrict__ out16,
                                                   float* __restrict__ sums_cur) {
    __shared__ float bnpart[4][2][NHD]; // 8 KB
    int p = blockIdx.x;
    int tid = threadIdx.x;
    int b = p & 7;
    int wave = tid >> 6;
    int lane = tid & 63;
    int head = lane >> 4;
    int li = lane & 15;
    int n = ((p >> 3) << 2) + wave;
    int g = b * NNODES + n;
    int start = offsets[n];
    int deg = offsets[n + 1] - start;
    const float* elb = el + (size_t)b * NNODES * NH;
    float er_nh = er[(size_t)g * NH + head];
    float* bw = &bnpart[wave][0][0]; // bw[c]=sum, bw[NHD+c]=sumsq

    if (deg == 0) {
        *(unsigned long long*)(out16 + (size_t)g * NHD + lane * 4) = 0ULL;
        int c4 = lane * 4;
#pragma unroll
        for (int j = 0; j < 4; ++j) {
            bw[c4 + j] = 0.0f;
            bw[NHD + c4 + j] = 0.0f;
        }
    } else if (deg <= 64) {
        // phase 1: lane li of each head-group owns edges li+16k
        float e[4], w[4];
        int s[4];
#pragma unroll
        for (int k = 0; k < 4; ++k) {
            int idx = k * 16 + li;
            if (idx < deg) {
                s[k] = csr_src[start + idx];
                float t = elb[s[k] * NH + head] + er_nh;
                e[k] = (t > 0.0f) ? t : 0.2f * t;
            } else {
                s[k] = 0;
                e[k] = -INFINITY;
            }
        }
        float mx = fmaxf(fmaxf(e[0], e[1]), fmaxf(e[2], e[3]));
#pragma unroll
        for (int o = 8; o; o >>= 1) mx = fmaxf(mx, __shfl_xor(mx, o));
        float sm = 0.0f;
#pragma unroll
        for (int k = 0; k < 4; ++k) {
            w[k] = __expf(e[k] - mx); // exp(-inf)=0 pads invalid slots
            sm += w[k];
        }
#pragma unroll
        for (int o = 8; o; o >>= 1) sm += __shfl_xor(sm, o);

        // phase 2: sub = lane>>5 serves edges j+sub; i32 = lane&31 -> 8 channels
        int sub = lane >> 5;
        int i32 = lane & 31;
        int hsel = (lane & 24) << 1; // channel head (i32>>3) * 16
        float smh = __shfl(sm, hsel); // denominator for the CHANNEL head
        const unsigned short* hrow = h16 + (size_t)b * NNODES * NHD + i32 * 8;
        float a0 = 0.f, a1 = 0.f, a2 = 0.f, a3 = 0.f;
        float a4 = 0.f, a5 = 0.f, a6 = 0.f, a7 = 0.f;
#define GATHER_CHUNK(K)                                                          \
        if (deg > (K) * 16) {                                                    \
            int cnt = deg - (K) * 16;                                            \
            cnt = (cnt > 16) ? 16 : cnt;                                         \
            int j = 0;                                                           \
            for (; j + 4 <= cnt; j += 4) {                                       \
                int sa = __shfl(s[K], j + sub);                                  \
                float wa = __shfl(w[K], hsel + j + sub);                         \
                int sb = __shfl(s[K], j + 2 + sub);                              \
                float wb = __shfl(w[K], hsel + j + 2 + sub);                     \
                halfx8 ha = *(const halfx8*)(hrow + (size_t)sa * NHD);           \
                halfx8 hb = *(const halfx8*)(hrow + (size_t)sb * NHD);           \
                a0 += wa * (float)ha[0]; a1 += wa * (float)ha[1];                \
                a2 += wa * (float)ha[2]; a3 += wa * (float)ha[3];                \
                a4 += wa * (float)ha[4]; a5 += wa * (float)ha[5];                \
                a6 += wa * (float)ha[6]; a7 += wa * (float)ha[7];                \
                a0 += wb * (float)hb[0]; a1 += wb * (float)hb[1];                \
                a2 += wb * (float)hb[2]; a3 += wb * (float)hb[3];                \
                a4 += wb * (float)hb[4]; a5 += wb * (float)hb[5];                \
                a6 += wb * (float)hb[6]; a7 += wb * (float)hb[7];                \
            }                                                                    \
            for (; j < cnt; j += 2) {                                            \
                int e2 = j + sub;                                                \
                bool valid = (e2 < cnt);                                         \
                int ec = valid ? e2 : (cnt - 1);                                 \
                int sa = __shfl(s[K], ec);                                       \
                float wa0 = __shfl(w[K], hsel + ec);                             \
                float wa = valid ? wa0 : 0.0f;                                   \
                halfx8 ha = *(const halfx8*)(hrow + (size_t)sa * NHD);           \
                a0 += wa * (float)ha[0]; a1 += wa * (float)ha[1];                \
                a2 += wa * (float)ha[2]; a3 += wa * (float)ha[3];                \
                a4 += wa * (float)ha[4]; a5 += wa * (float)ha[5];                \
                a6 += wa * (float)ha[6]; a7 += wa * (float)ha[7];                \
            }                                                                    \
        }
        GATHER_CHUNK(0)
        GATHER_CHUNK(1)
        GATHER_CHUNK(2)
        GATHER_CHUNK(3)
#undef GATHER_CHUNK
        a0 += __shfl_xor(a0, 32); a1 += __shfl_xor(a1, 32);
        a2 += __shfl_xor(a2, 32); a3 += __shfl_xor(a3, 32);
        a4 += __shfl_xor(a4, 32); a5 += __shfl_xor(a5, 32);
        a6 += __shfl_xor(a6, 32); a7 += __shfl_xor(a7, 32);
        if (sub == 0) {
            float inv = 1.0f / smh;
            halfx8 o8;
            o8[0] = (_Float16)(a0 * inv); o8[1] = (_Float16)(a1 * inv);
            o8[2] = (_Float16)(a2 * inv); o8[3] = (_Float16)(a3 * inv);
            o8[4] = (_Float16)(a4 * inv); o8[5] = (_Float16)(a5 * inv);
            o8[6] = (_Float16)(a6 * inv); o8[7] = (_Float16)(a7 * inv);
            *(halfx8*)(out16 + (size_t)g * NHD + i32 * 8) = o8;
            int c8 = i32 * 8;
#pragma unroll
            for (int j = 0; j < 8; ++j) {
                float v = (float)o8[j];
                bw[c8 + j] = v;
                bw[NHD + c8 + j] = v * v;
            }
        }
    } else {
        // generic fallback (deg > 64, rare)
        const unsigned short* hbase = h16 + (size_t)b * NNODES * NHD + lane * 4;
        float mx = -INFINITY;
        for (int i = li; i < deg; i += 16) {
            int s2 = csr_src[start + i];
            float t = elb[s2 * NH + head] + er_nh;
            t = (t > 0.0f) ? t : 0.2f * t;
            mx = fmaxf(mx, t);
        }
#pragma unroll
        for (int o = 8; o; o >>= 1) mx = fmaxf(mx, __shfl_xor(mx, o));
        float sm = 0.0f;
        for (int i = li; i < deg; i += 16) {
            int s2 = csr_src[start + i];
            float t = elb[s2 * NH + head] + er_nh;
            t = (t > 0.0f) ? t : 0.2f * t;
            sm += __expf(t - mx);
        }
#pragma unroll
        for (int o = 8; o; o >>= 1) sm += __shfl_xor(sm, o);
        float a0 = 0.f, a1 = 0.f, a2 = 0.f, a3 = 0.f;
        for (int j = 0; j < deg; ++j) {
            int s2 = csr_src[start + j];
            float t = elb[s2 * NH + head] + er_nh;
            t = (t > 0.0f) ? t : 0.2f * t;
            float wj = __expf(t - mx);
            halfx4 hv = *(const halfx4*)(hbase + (size_t)s2 * NHD);
            a0 += wj * (float)hv[0];
            a1 += wj * (float)hv[1];
            a2 += wj * (float)hv[2];
            a3 += wj * (float)hv[3];
        }
        float inv = 1.0f / sm;
        halfx4 o4;
        o4[0] = (_Float16)(a0 * inv);
        o4[1] = (_Float16)(a1 * inv);
        o4[2] = (_Float16)(a2 * inv);
        o4[3] = (_Float16)(a3 * inv);
        *(halfx4*)(out16 + (size_t)g * NHD + lane * 4) = o4;
        int c4 = lane * 4;
#pragma unroll
        for (int j = 0; j < 4; ++j) {
            float v = (float)o4[j];
            bw[c4 + j] = v;
            bw[NHD + c4 + j] = v * v;
        }
    }
    __syncthreads();
    {
        int c = tid;
        float s = bnpart[0][0][c] + bnpart[1][0][c] + bnpart[2][0][c] + bnpart[3][0][c];
        float s2 = bnpart[0][1][c] + bnpart[1][1][c] + bnpart[2][1][c] + bnpart[3][1][c];
        float* sr = sums_cur + (p & (NREP - 1)) * 2 * NHD;
        atomicAdd(&sr[c], s);
        atomicAdd(&sr[NHD + c], s2);
    }
}

// ---------------- output head (inline BN+lrelu) + f16 window shift ----------------

__global__ __launch_bounds__(256) void headout_kernel(const unsigned short* __restrict__ x16,
                                                      const float* __restrict__ sums,
                                                      const float* __restrict__ gamma,
                                                      const float* __restrict__ beta,
                                                      const float* __restrict__ Wout,
                                                      const float* __restrict__ bout,
                                                      float* __restrict__ out,
                                                      unsigned short* __restrict__ xx16, int t) {
    __shared__ float bsc[NHD];
    __shared__ float bsh[NHD];
    {
        int c = threadIdx.x;
        float s = 0.0f, s2 = 0.0f;
        for (int r2 = 0; r2 < NREP; ++r2) {
            s += sums[r2 * 2 * NHD + c];
            s2 += sums[r2 * 2 * NHD + NHD + c];
        }
        const float invn = 1.0f / (float)ROWS;
        float mu = s * invn;
        float var = s2 * invn - mu * mu;
        float sc = rsqrtf(var + BNEPS) * gamma[c];
        bsc[c] = sc;
        bsh[c] = beta[c] - mu * sc;
    }
    __syncthreads();

    int wave = threadIdx.x >> 6;
    int lane = threadIdx.x & 63;
    int g = blockIdx.x * 4 + wave;
    int c0 = lane * 4;
    halfx4 hv = *(const halfx4*)(x16 + (size_t)g * NHD + c0);
    float vv[4];
#pragma unroll
    for (int j = 0; j < 4; ++j) {
        float x = fmaf((float)hv[j], bsc[c0 + j], bsh[c0 + j]);
        vv[j] = (x > 0.0f) ? x : 0.01f * x;
    }
    float r0 = vv[0] * Wout[(c0 + 0) * NOUT + 0] + vv[1] * Wout[(c0 + 1) * NOUT + 0] +
               vv[2] * Wout[(c0 + 2) * NOUT + 0] + vv[3] * Wout[(c0 + 3) * NOUT + 0];
    float r1 = vv[0] * Wout[(c0 + 0) * NOUT + 1] + vv[1] * Wout[(c0 + 1) * NOUT + 1] +
               vv[2] * Wout[(c0 + 2) * NOUT + 1] + vv[3] * Wout[(c0 + 3) * NOUT + 1];
    float r2 = vv[0] * Wout[(c0 + 0) * NOUT + 2] + vv[1] * Wout[(c0 + 1) * NOUT + 2] +
               vv[2] * Wout[(c0 + 2) * NOUT + 2] + vv[3] * Wout[(c0 + 3) * NOUT + 2];
#pragma unroll
    for (int o = 32; o; o >>= 1) {
        r0 += __shfl_xor(r0, o);
        r1 += __shfl_xor(r1, o);
        r2 += __shfl_xor(r2, o);
    }
    float o0 = r0 + bout[0], o1 = r1 + bout[1], o2 = r2 + bout[2];
    if (lane == 0) {
        float* op = out + ((size_t)g * NT + t) * NOUT;
        op[0] = o0;
        op[1] = o1;
        op[2] = o2;
    }
    float oldv = (lane < NIN) ? h2f(xx16[(size_t)g * K0PAD + lane]) : 0.0f;
    float shifted = __shfl(oldv, lane + 3);
    float newv = (lane < 27) ? shifted : (lane == 27 ? o0 : (lane == 28 ? o1 : o2));
    if (lane < NIN) xx16[(size_t)g * K0PAD + lane] = f2h(newv);
}

// ---------------- launch ----------------

extern "C" void kernel_launch(void* const* d_in, const int* in_sizes, int n_in,
                              void* d_out, int out_size, void* d_ws, size_t ws_size,
                              hipStream_t stream) {
    const float* xx = (const float*)d_in[0];
    const int* src = (const int*)d_in[1];
    const int* dst = (const int*)d_in[2];
    const float* W[4] = {(const float*)d_in[3], (const float*)d_in[8],
                         (const float*)d_in[13], (const float*)d_in[18]};
    const float* al[4] = {(const float*)d_in[4], (const float*)d_in[9],
                          (const float*)d_in[14], (const float*)d_in[19]};
    const float* ar[4] = {(const float*)d_in[5], (const float*)d_in[10],
                          (const float*)d_in[15], (const float*)d_in[20]};
    const float* gamma[4] = {(const float*)d_in[6], (const float*)d_in[11],
                             (const float*)d_in[16], (const float*)d_in[21]};
    const float* beta[4] = {(const float*)d_in[7], (const float*)d_in[12],
                            (const float*)d_in[17], (const float*)d_in[22]};
    const float* W_out = (const float*)d_in[23];
    const float* b_out = (const float*)d_in[24];
    float* out = (float*)d_out;

    // workspace carve
    float* wsf = (float*)d_ws;
    float* el = wsf;                                        // ROWS*NH
    float* er = el + (size_t)ROWS * NH;                     // ROWS*NH
    float* sumsA = er + (size_t)ROWS * NH;                  // NREP*2*NHD
    float* sumsB = sumsA + NREP * 2 * NHD;                  // NREP*2*NHD
    unsigned short* h16 = (unsigned short*)(sumsB + NREP * 2 * NHD); // ROWS*NHD
    unsigned short* act16 = h16 + (size_t)ROWS * NHD;       // ROWS*NHD (attn out)
    unsigned short* xx16 = act16 + (size_t)ROWS * NHD;      // ROWS*K0PAD
    unsigned short* Wt0 = xx16 + (size_t)ROWS * K0PAD;      // 256*K0PAD
    unsigned short* Wt1 = Wt0 + 256 * K0PAD;                // 256*256
    unsigned short* Wt2 = Wt1 + 256 * NHD;
    unsigned short* Wt3 = Wt2 + 256 * NHD;
    int* counts = (int*)(Wt3 + 256 * NHD);                  // NNODES
    int* offsets = counts + NNODES;                         // NNODES+1 (+pad)
    int* cursor = offsets + NNODES + 8;                     // NNODES
    int* csr_src = cursor + NNODES;                         // NEDGES
    const unsigned short* Wt[4] = {Wt0, Wt1, Wt2, Wt3};

    // ---- CSR build + packing (once per launch) ----
    hipMemsetAsync(counts, 0, NNODES * sizeof(int), stream);
    count_kernel<<<(NEDGES + 255) / 256, 256, 0, stream>>>(dst, counts, NEDGES);
    scan_kernel<<<1, 1024, 0, stream>>>(counts, offsets, NNODES);
    hipMemsetAsync(cursor, 0, NNODES * sizeof(int), stream);
    fill_kernel<<<(NEDGES + 255) / 256, 256, 0, stream>>>(src, dst, offsets, cursor,
                                                          csr_src, NEDGES);
    pack_xx_kernel<<<(ROWS * K0PAD + 255) / 256, 256, 0, stream>>>(xx, xx16);
    packWt_kernel<<<dim3(256, 4), 256, 0, stream>>>(W[0], W[1], W[2], W[3],
                                                    (unsigned short*)Wt0,
                                                    (unsigned short*)Wt1,
                                                    (unsigned short*)Wt2,
                                                    (unsigned short*)Wt3);

    int idx = 0;
    for (int t = 0; t < NT; ++t) {
        for (int l = 0; l < 4; ++l) {
            const unsigned short* A16 = (l == 0) ? xx16 : act16;
            int K = (l == 0) ? K0PAD : NHD;
            int apply_bn = (l > 0) ? 1 : 0;
            const float* pg = gamma[(l > 0) ? l - 1 : 0];
            const float* pb = beta[(l > 0) ? l - 1 : 0];
            float* cur = (idx & 1) ? sumsB : sumsA;   // attn(idx) fills this
            const float* prev = (idx & 1) ? sumsA : sumsB; // attn(idx-1) filled this
            gemm_mfma_kernel<<<ROWS / BM, 256, 0, stream>>>(A16, Wt[l], al[l], ar[l],
                                                            prev, cur, pg, pb, apply_bn,
                                                            h16, el, er, K);
            attn_kernel<<<ROWS / 4, 256, 0, stream>>>(h16, el, er, offsets, csr_src,
                                                      act16, cur);
            ++idx;
        }
        // last attn of step t had parity (t*4+3)&1 == 1 -> sumsB
        headout_kernel<<<ROWS / 4, 256, 0, stream>>>(act16, sumsB, gamma[3], beta[3],
                                                     W_out, b_out, out, xx16, t);
    }
}

// Round 13
// 1336.111 us; speedup vs baseline: 1.1430x; 1.1430x over previous
//
#include <hip/hip_runtime.h>
#include <math.h>

#define NNODES 5000
#define NEDGES 80000
#define NB 8
#define NIN 30
#define K0PAD 32
#define NH 4
#define ND 64
#define NHD 256
#define NT 5
#define NOUT 3
#define ROWS (NB * NNODES) // 40000
#define BNEPS 1e-5f
#define KP 40   // LDS k-stride for A tile (shorts); 80B rows -> 2-way alias (free)
#define NREP 64 // sums[] replicas (attn-fused BN: 10000 blocks / 64 = 156 per addr)
#define BM 32   // gemm M-tile (32 -> 1250 blocks, 4.9/CU co-residency)

#define GLOBAL_AS __attribute__((address_space(1)))
#define LDS_AS __attribute__((address_space(3)))

typedef short shortx8 __attribute__((ext_vector_type(8)));
typedef _Float16 halfx8 __attribute__((ext_vector_type(8)));
typedef _Float16 halfx4 __attribute__((ext_vector_type(4)));
typedef _Float16 halfx2 __attribute__((ext_vector_type(2)));
typedef float floatx4 __attribute__((ext_vector_type(4)));

static __device__ __forceinline__ unsigned short f2h(float f) {
    union { _Float16 h; unsigned short u; } v;
    v.h = (_Float16)f;
    return v.u;
}
static __device__ __forceinline__ float h2f(unsigned short u) {
    union { _Float16 h; unsigned short u; } v;
    v.u = u;
    return (float)v.h;
}

// ---------------- CSR build ----------------

__global__ void count_kernel(const int* __restrict__ dst, int* __restrict__ counts, int n) {
    int e = blockIdx.x * blockDim.x + threadIdx.x;
    if (e < n) atomicAdd(&counts[dst[e]], 1);
}

__global__ __launch_bounds__(1024) void scan_kernel(const int* __restrict__ counts,
                                                    int* __restrict__ offsets, int n) {
    __shared__ int smem[1024];
    const int CH = 5;
    int tid = threadIdx.x;
    int base = tid * CH;
    int loc[CH];
    int s = 0;
    for (int j = 0; j < CH; ++j) {
        int i = base + j;
        int v = (i < n) ? counts[i] : 0;
        loc[j] = s;
        s += v;
    }
    smem[tid] = s;
    __syncthreads();
    for (int off = 1; off < 1024; off <<= 1) {
        int v = (tid >= off) ? smem[tid - off] : 0;
        __syncthreads();
        smem[tid] += v;
        __syncthreads();
    }
    int excl = smem[tid] - s;
    for (int j = 0; j < CH; ++j) {
        int i = base + j;
        if (i < n) offsets[i] = excl + loc[j];
    }
    if (tid == 1023) offsets[n] = smem[1023];
}

__global__ void fill_kernel(const int* __restrict__ src, const int* __restrict__ dst,
                            const int* __restrict__ offsets, int* __restrict__ cursor,
                            int* __restrict__ csr_src, int n) {
    int e = blockIdx.x * blockDim.x + threadIdx.x;
    if (e >= n) return;
    int d = dst[e];
    int pos = offsets[d] + atomicAdd(&cursor[d], 1);
    csr_src[pos] = src[e];
}

// ---------------- packing ----------------

__global__ void pack_xx_kernel(const float* __restrict__ xx, unsigned short* __restrict__ xx16) {
    int idx = blockIdx.x * blockDim.x + threadIdx.x;
    if (idx >= ROWS * K0PAD) return;
    int g = idx >> 5;
    int k = idx & 31;
    float v = (k < NIN) ? xx[(size_t)g * NIN + k] : 0.0f;
    xx16[idx] = f2h(v);
}

// WtP: per 32-k tile, 16B chunks (n,quad) at swizzled pos p = n*4 + (quad ^ ((n>>1)&3)).
__global__ void packWt_kernel(const float* __restrict__ W0, const float* __restrict__ W1,
                              const float* __restrict__ W2, const float* __restrict__ W3,
                              unsigned short* __restrict__ P0, unsigned short* __restrict__ P1,
                              unsigned short* __restrict__ P2, unsigned short* __restrict__ P3) {
    int l = blockIdx.y;
    const float* W = (l == 0) ? W0 : (l == 1) ? W1 : (l == 2) ? W2 : W3;
    unsigned short* WtP = (l == 0) ? P0 : (l == 1) ? P1 : (l == 2) ? P2 : P3;
    int Kin = (l == 0) ? NIN : NHD;
    int Kpad = (l == 0) ? K0PAD : NHD;
    int n = blockIdx.x;
    int k = threadIdx.x;
    if (k < Kpad) {
        float v = (k < Kin) ? W[(size_t)k * NHD + n] : 0.0f;
        int t = k >> 5;
        int quad = (k >> 3) & 3;
        int j = k & 7;
        int p = n * 4 + (quad ^ ((n >> 1) & 3));
        WtP[(size_t)t * (NHD * 32) + p * 8 + j] = f2h(v);
    }
}

// ---------------- BN finalize: 64 replicas -> scale/shift table (once) ----------------
// 1 block x 256 thr. Also zeroes sums for the next attn (same thread, after read).

__global__ __launch_bounds__(256) void bnfinal_kernel(float* __restrict__ sums,
                                                      const float* __restrict__ gamma,
                                                      const float* __restrict__ beta,
                                                      float* __restrict__ bnss) {
    int c = threadIdx.x;
    float s = 0.0f, s2 = 0.0f;
#pragma unroll
    for (int r = 0; r < NREP; ++r) {
        s += sums[r * 2 * NHD + c];
        s2 += sums[r * 2 * NHD + NHD + c];
        sums[r * 2 * NHD + c] = 0.0f;
        sums[r * 2 * NHD + NHD + c] = 0.0f;
    }
    const float invn = 1.0f / (float)ROWS;
    float mu = s * invn;
    float var = s2 * invn - mu * mu;
    float sc = rsqrtf(var + BNEPS) * gamma[c];
    bnss[c] = sc;
    bnss[NHD + c] = beta[c] - mu * sc;
}

// ---------------- MFMA GEMM + fused BN(prev layer) on A + fused el/er ----------------
// BN scale/shift read from the precomputed bnss table (2 loads/thread).

__global__ __launch_bounds__(256) void gemm_mfma_kernel(
    const unsigned short* __restrict__ A, const unsigned short* __restrict__ Wt,
    const float* __restrict__ alw, const float* __restrict__ arw,
    const float* __restrict__ bnss, int apply_bn,
    unsigned short* __restrict__ C16, float* __restrict__ el, float* __restrict__ er,
    int K) {
    __shared__ __align__(16) short As[BM * KP];
    __shared__ __align__(16) short Bs[256 * 32];
    __shared__ float bn_scale[NHD];
    __shared__ float bn_shift[NHD];
    int tid = threadIdx.x;
    if (apply_bn) {
        bn_scale[tid] = bnss[tid];
        bn_shift[tid] = bnss[NHD + tid];
    }
    __syncthreads();

    int wave = tid >> 6; // head
    int lane = tid & 63;
    int c = lane & 15;
    int quad = lane >> 4;
    int xorv = (c >> 1) & 3;
    int row0 = blockIdx.x * BM;

    floatx4 acc[2][4];
#pragma unroll
    for (int mt = 0; mt < 2; ++mt)
#pragma unroll
        for (int nt = 0; nt < 4; ++nt) acc[mt][nt] = (floatx4){0.f, 0.f, 0.f, 0.f};

    int r = tid >> 2;   // 0..63 (only <BM used)
    int seg = tid & 3;
    for (int k0 = 0; k0 < K; k0 += 32) {
        const unsigned short* gB = Wt + (size_t)(k0 >> 5) * (NHD * 32);
#pragma unroll
        for (int i = 0; i < 4; ++i) {
            int ci = i * 256 + tid;
            __builtin_amdgcn_global_load_lds(
                (const GLOBAL_AS unsigned int*)(gB + ci * 8),
                (LDS_AS unsigned int*)(&Bs[ci * 8]), 16, 0, 0);
        }
        if (r < BM) {
            shortx8 v = *(const shortx8*)(A + (size_t)(row0 + r) * K + k0 + seg * 8);
            if (apply_bn) {
                halfx8 hv = *(halfx8*)&v;
                int kg = k0 + seg * 8;
#pragma unroll
                for (int j = 0; j < 8; ++j) {
                    float x = (float)hv[j];
                    x = fmaf(x, bn_scale[kg + j], bn_shift[kg + j]);
                    x = (x > 0.0f) ? x : 0.01f * x;
                    hv[j] = (_Float16)x;
                }
                v = *(shortx8*)&hv;
            }
            *(shortx8*)(&As[r * KP + seg * 8]) = v;
        }
        __syncthreads();
        halfx8 a[2], b[4];
#pragma unroll
        for (int mt = 0; mt < 2; ++mt)
            a[mt] = *(const halfx8*)(&As[(mt * 16 + c) * KP + quad * 8]);
#pragma unroll
        for (int nt = 0; nt < 4; ++nt) {
            int pq = (wave * 64 + nt * 16 + c) * 4 + (quad ^ xorv);
            b[nt] = *(const halfx8*)(&Bs[pq * 8]);
        }
#pragma unroll
        for (int mt = 0; mt < 2; ++mt)
#pragma unroll
            for (int nt = 0; nt < 4; ++nt)
                acc[mt][nt] = __builtin_amdgcn_mfma_f32_16x16x32_f16(a[mt], b[nt],
                                                                     acc[mt][nt], 0, 0, 0);
        __syncthreads();
    }

    float alv[4], arv[4];
#pragma unroll
    for (int nt = 0; nt < 4; ++nt) {
        alv[nt] = alw[wave * 64 + nt * 16 + c];
        arv[nt] = arw[wave * 64 + nt * 16 + c];
    }
#pragma unroll
    for (int mt = 0; mt < 2; ++mt) {
#pragma unroll
        for (int rr = 0; rr < 4; ++rr) {
            int row = row0 + mt * 16 + quad * 4 + rr;
            float pl = 0.0f, pr = 0.0f;
#pragma unroll
            for (int nt = 0; nt < 4; ++nt) {
                float v = acc[mt][nt][rr];
                C16[(size_t)row * NHD + wave * 64 + nt * 16 + c] = f2h(v);
                pl += v * alv[nt];
                pr += v * arv[nt];
            }
#pragma unroll
            for (int o = 1; o < 16; o <<= 1) {
                pl += __shfl_xor(pl, o);
                pr += __shfl_xor(pr, o);
            }
            if (c == mt * 4 + rr) {
                el[(size_t)row * NH + wave] = pl;
                er[(size_t)row * NH + wave] = pr;
            }
        }
    }
}

// ---------------- edge softmax + aggregate + FUSED BN partial reduce ----------------
// Wave per node. Phase 1 logits once per node; phase 2 coalesced halfx8 gather.
// Epilogue: per-wave LDS partials, one barrier, 2 atomics/thread into replica blk&63.

__global__ __launch_bounds__(256) void attn_kernel(const unsigned short* __restrict__ h16,
                                                   const float* __restrict__ el,
                                                   const float* __restrict__ er,
                                                   const int* __restrict__ offsets,
                                                   const int* __restrict__ csr_src,
                                                   unsigned short* __restrict__ out16,
                                                   float* __restrict__ sums_cur) {
    __shared__ float bnpart[4][2][NHD]; // 8 KB
    int p = blockIdx.x;
    int tid = threadIdx.x;
    int b = p & 7;
    int wave = tid >> 6;
    int lane = tid & 63;
    int head = lane >> 4;
    int li = lane & 15;
    int n = ((p >> 3) << 2) + wave;
    int g = b * NNODES + n;
    int start = offsets[n];
    int deg = offsets[n + 1] - start;
    const float* elb = el + (size_t)b * NNODES * NH;
    float er_nh = er[(size_t)g * NH + head];
    float* bw = &bnpart[wave][0][0]; // bw[c]=sum, bw[NHD+c]=sumsq

    if (deg == 0) {
        *(unsigned long long*)(out16 + (size_t)g * NHD + lane * 4) = 0ULL;
        int c4 = lane * 4;
#pragma unroll
        for (int j = 0; j < 4; ++j) {
            bw[c4 + j] = 0.0f;
            bw[NHD + c4 + j] = 0.0f;
        }
    } else if (deg <= 64) {
        // phase 1: lane li of each head-group owns edges li+16k
        float e[4], w[4];
        int s[4];
#pragma unroll
        for (int k = 0; k < 4; ++k) {
            int idx = k * 16 + li;
            if (idx < deg) {
                s[k] = csr_src[start + idx];
                float t = elb[s[k] * NH + head] + er_nh;
                e[k] = (t > 0.0f) ? t : 0.2f * t;
            } else {
                s[k] = 0;
                e[k] = -INFINITY;
            }
        }
        float mx = fmaxf(fmaxf(e[0], e[1]), fmaxf(e[2], e[3]));
#pragma unroll
        for (int o = 8; o; o >>= 1) mx = fmaxf(mx, __shfl_xor(mx, o));
        float sm = 0.0f;
#pragma unroll
        for (int k = 0; k < 4; ++k) {
            w[k] = __expf(e[k] - mx); // exp(-inf)=0 pads invalid slots
            sm += w[k];
        }
#pragma unroll
        for (int o = 8; o; o >>= 1) sm += __shfl_xor(sm, o);

        // phase 2: sub = lane>>5 serves edges j+sub; i32 = lane&31 -> 8 channels
        int sub = lane >> 5;
        int i32 = lane & 31;
        int hsel = (lane & 24) << 1; // channel head (i32>>3) * 16
        float smh = __shfl(sm, hsel); // denominator for the CHANNEL head
        const unsigned short* hrow = h16 + (size_t)b * NNODES * NHD + i32 * 8;
        float a0 = 0.f, a1 = 0.f, a2 = 0.f, a3 = 0.f;
        float a4 = 0.f, a5 = 0.f, a6 = 0.f, a7 = 0.f;
#define GATHER_CHUNK(K)                                                          \
        if (deg > (K) * 16) {                                                    \
            int cnt = deg - (K) * 16;                                            \
            cnt = (cnt > 16) ? 16 : cnt;                                         \
            int j = 0;                                                           \
            for (; j + 4 <= cnt; j += 4) {                                       \
                int sa = __shfl(s[K], j + sub);                                  \
                float wa = __shfl(w[K], hsel + j + sub);                         \
                int sb = __shfl(s[K], j + 2 + sub);                              \
                float wb = __shfl(w[K], hsel + j + 2 + sub);                     \
                halfx8 ha = *(const halfx8*)(hrow + (size_t)sa * NHD);           \
                halfx8 hb = *(const halfx8*)(hrow + (size_t)sb * NHD);           \
                a0 += wa * (float)ha[0]; a1 += wa * (float)ha[1];                \
                a2 += wa * (float)ha[2]; a3 += wa * (float)ha[3];                \
                a4 += wa * (float)ha[4]; a5 += wa * (float)ha[5];                \
                a6 += wa * (float)ha[6]; a7 += wa * (float)ha[7];                \
                a0 += wb * (float)hb[0]; a1 += wb * (float)hb[1];                \
                a2 += wb * (float)hb[2]; a3 += wb * (float)hb[3];                \
                a4 += wb * (float)hb[4]; a5 += wb * (float)hb[5];                \
                a6 += wb * (float)hb[6]; a7 += wb * (float)hb[7];                \
            }                                                                    \
            for (; j < cnt; j += 2) {                                            \
                int e2 = j + sub;                                                \
                bool valid = (e2 < cnt);                                         \
                int ec = valid ? e2 : (cnt - 1);                                 \
                int sa = __shfl(s[K], ec);                                       \
                float wa0 = __shfl(w[K], hsel + ec);                             \
                float wa = valid ? wa0 : 0.0f;                                   \
                halfx8 ha = *(const halfx8*)(hrow + (size_t)sa * NHD);           \
                a0 += wa * (float)ha[0]; a1 += wa * (float)ha[1];                \
                a2 += wa * (float)ha[2]; a3 += wa * (float)ha[3];                \
                a4 += wa * (float)ha[4]; a5 += wa * (float)ha[5];                \
                a6 += wa * (float)ha[6]; a7 += wa * (float)ha[7];                \
            }                                                                    \
        }
        GATHER_CHUNK(0)
        GATHER_CHUNK(1)
        GATHER_CHUNK(2)
        GATHER_CHUNK(3)
#undef GATHER_CHUNK
        a0 += __shfl_xor(a0, 32); a1 += __shfl_xor(a1, 32);
        a2 += __shfl_xor(a2, 32); a3 += __shfl_xor(a3, 32);
        a4 += __shfl_xor(a4, 32); a5 += __shfl_xor(a5, 32);
        a6 += __shfl_xor(a6, 32); a7 += __shfl_xor(a7, 32);
        if (sub == 0) {
            float inv = 1.0f / smh;
            halfx8 o8;
            o8[0] = (_Float16)(a0 * inv); o8[1] = (_Float16)(a1 * inv);
            o8[2] = (_Float16)(a2 * inv); o8[3] = (_Float16)(a3 * inv);
            o8[4] = (_Float16)(a4 * inv); o8[5] = (_Float16)(a5 * inv);
            o8[6] = (_Float16)(a6 * inv); o8[7] = (_Float16)(a7 * inv);
            *(halfx8*)(out16 + (size_t)g * NHD + i32 * 8) = o8;
            int c8 = i32 * 8;
#pragma unroll
            for (int j = 0; j < 8; ++j) {
                float v = (float)o8[j];
                bw[c8 + j] = v;
                bw[NHD + c8 + j] = v * v;
            }
        }
    } else {
        // generic fallback (deg > 64, rare)
        const unsigned short* hbase = h16 + (size_t)b * NNODES * NHD + lane * 4;
        float mx = -INFINITY;
        for (int i = li; i < deg; i += 16) {
            int s2 = csr_src[start + i];
            float t = elb[s2 * NH + head] + er_nh;
            t = (t > 0.0f) ? t : 0.2f * t;
            mx = fmaxf(mx, t);
        }
#pragma unroll
        for (int o = 8; o; o >>= 1) mx = fmaxf(mx, __shfl_xor(mx, o));
        float sm = 0.0f;
        for (int i = li; i < deg; i += 16) {
            int s2 = csr_src[start + i];
            float t = elb[s2 * NH + head] + er_nh;
            t = (t > 0.0f) ? t : 0.2f * t;
            sm += __expf(t - mx);
        }
#pragma unroll
        for (int o = 8; o; o >>= 1) sm += __shfl_xor(sm, o);
        float a0 = 0.f, a1 = 0.f, a2 = 0.f, a3 = 0.f;
        for (int j = 0; j < deg; ++j) {
            int s2 = csr_src[start + j];
            float t = elb[s2 * NH + head] + er_nh;
            t = (t > 0.0f) ? t : 0.2f * t;
            float wj = __expf(t - mx);
            halfx4 hv = *(const halfx4*)(hbase + (size_t)s2 * NHD);
            a0 += wj * (float)hv[0];
            a1 += wj * (float)hv[1];
            a2 += wj * (float)hv[2];
            a3 += wj * (float)hv[3];
        }
        float inv = 1.0f / sm;
        halfx4 o4;
        o4[0] = (_Float16)(a0 * inv);
        o4[1] = (_Float16)(a1 * inv);
        o4[2] = (_Float16)(a2 * inv);
        o4[3] = (_Float16)(a3 * inv);
        *(halfx4*)(out16 + (size_t)g * NHD + lane * 4) = o4;
        int c4 = lane * 4;
#pragma unroll
        for (int j = 0; j < 4; ++j) {
            float v = (float)o4[j];
            bw[c4 + j] = v;
            bw[NHD + c4 + j] = v * v;
        }
    }
    __syncthreads();
    {
        int c = tid;
        float s = bnpart[0][0][c] + bnpart[1][0][c] + bnpart[2][0][c] + bnpart[3][0][c];
        float s2 = bnpart[0][1][c] + bnpart[1][1][c] + bnpart[2][1][c] + bnpart[3][1][c];
        float* sr = sums_cur + (p & (NREP - 1)) * 2 * NHD;
        atomicAdd(&sr[c], s);
        atomicAdd(&sr[NHD + c], s2);
    }
}

// ---------------- output head (BN table from bnss) + f16 window shift ----------------

__global__ __launch_bounds__(256) void headout_kernel(const unsigned short* __restrict__ x16,
                                                      const float* __restrict__ bnss,
                                                      const float* __restrict__ Wout,
                                                      const float* __restrict__ bout,
                                                      float* __restrict__ out,
                                                      unsigned short* __restrict__ xx16, int t) {
    __shared__ float bsc[NHD];
    __shared__ float bsh[NHD];
    {
        int c = threadIdx.x;
        bsc[c] = bnss[c];
        bsh[c] = bnss[NHD + c];
    }
    __syncthreads();

    int wave = threadIdx.x >> 6;
    int lane = threadIdx.x & 63;
    int g = blockIdx.x * 4 + wave;
    int c0 = lane * 4;
    halfx4 hv = *(const halfx4*)(x16 + (size_t)g * NHD + c0);
    float vv[4];
#pragma unroll
    for (int j = 0; j < 4; ++j) {
        float x = fmaf((float)hv[j], bsc[c0 + j], bsh[c0 + j]);
        vv[j] = (x > 0.0f) ? x : 0.01f * x;
    }
    float r0 = vv[0] * Wout[(c0 + 0) * NOUT + 0] + vv[1] * Wout[(c0 + 1) * NOUT + 0] +
               vv[2] * Wout[(c0 + 2) * NOUT + 0] + vv[3] * Wout[(c0 + 3) * NOUT + 0];
    float r1 = vv[0] * Wout[(c0 + 0) * NOUT + 1] + vv[1] * Wout[(c0 + 1) * NOUT + 1] +
               vv[2] * Wout[(c0 + 2) * NOUT + 1] + vv[3] * Wout[(c0 + 3) * NOUT + 1];
    float r2 = vv[0] * Wout[(c0 + 0) * NOUT + 2] + vv[1] * Wout[(c0 + 1) * NOUT + 2] +
               vv[2] * Wout[(c0 + 2) * NOUT + 2] + vv[3] * Wout[(c0 + 3) * NOUT + 2];
#pragma unroll
    for (int o = 32; o; o >>= 1) {
        r0 += __shfl_xor(r0, o);
        r1 += __shfl_xor(r1, o);
        r2 += __shfl_xor(r2, o);
    }
    float o0 = r0 + bout[0], o1 = r1 + bout[1], o2 = r2 + bout[2];
    if (lane == 0) {
        float* op = out + ((size_t)g * NT + t) * NOUT;
        op[0] = o0;
        op[1] = o1;
        op[2] = o2;
    }
    float oldv = (lane < NIN) ? h2f(xx16[(size_t)g * K0PAD + lane]) : 0.0f;
    float shifted = __shfl(oldv, lane + 3);
    float newv = (lane < 27) ? shifted : (lane == 27 ? o0 : (lane == 28 ? o1 : o2));
    if (lane < NIN) xx16[(size_t)g * K0PAD + lane] = f2h(newv);
}

// ---------------- launch ----------------

extern "C" void kernel_launch(void* const* d_in, const int* in_sizes, int n_in,
                              void* d_out, int out_size, void* d_ws, size_t ws_size,
                              hipStream_t stream) {
    const float* xx = (const float*)d_in[0];
    const int* src = (const int*)d_in[1];
    const int* dst = (const int*)d_in[2];
    const float* W[4] = {(const float*)d_in[3], (const float*)d_in[8],
                         (const float*)d_in[13], (const float*)d_in[18]};
    const float* al[4] = {(const float*)d_in[4], (const float*)d_in[9],
                          (const float*)d_in[14], (const float*)d_in[19]};
    const float* ar[4] = {(const float*)d_in[5], (const float*)d_in[10],
                          (const float*)d_in[15], (const float*)d_in[20]};
    const float* gamma[4] = {(const float*)d_in[6], (const float*)d_in[11],
                             (const float*)d_in[16], (const float*)d_in[21]};
    const float* beta[4] = {(const float*)d_in[7], (const float*)d_in[12],
                            (const float*)d_in[17], (const float*)d_in[22]};
    const float* W_out = (const float*)d_in[23];
    const float* b_out = (const float*)d_in[24];
    float* out = (float*)d_out;

    // workspace carve
    float* wsf = (float*)d_ws;
    float* el = wsf;                                        // ROWS*NH
    float* er = el + (size_t)ROWS * NH;                     // ROWS*NH
    float* sums = er + (size_t)ROWS * NH;                   // NREP*2*NHD
    float* bnss = sums + NREP * 2 * NHD;                    // 2*NHD (scale|shift)
    unsigned short* h16 = (unsigned short*)(bnss + 2 * NHD); // ROWS*NHD
    unsigned short* act16 = h16 + (size_t)ROWS * NHD;       // ROWS*NHD (attn out)
    unsigned short* xx16 = act16 + (size_t)ROWS * NHD;      // ROWS*K0PAD
    unsigned short* Wt0 = xx16 + (size_t)ROWS * K0PAD;      // 256*K0PAD
    unsigned short* Wt1 = Wt0 + 256 * K0PAD;                // 256*256
    unsigned short* Wt2 = Wt1 + 256 * NHD;
    unsigned short* Wt3 = Wt2 + 256 * NHD;
    int* counts = (int*)(Wt3 + 256 * NHD);                  // NNODES
    int* offsets = counts + NNODES;                         // NNODES+1 (+pad)
    int* cursor = offsets + NNODES + 8;                     // NNODES
    int* csr_src = cursor + NNODES;                         // NEDGES
    const unsigned short* Wt[4] = {Wt0, Wt1, Wt2, Wt3};

    // ---- CSR build + packing (once per launch) ----
    hipMemsetAsync(counts, 0, NNODES * sizeof(int), stream);
    hipMemsetAsync(sums, 0, NREP * 2 * NHD * sizeof(float), stream);
    count_kernel<<<(NEDGES + 255) / 256, 256, 0, stream>>>(dst, counts, NEDGES);
    scan_kernel<<<1, 1024, 0, stream>>>(counts, offsets, NNODES);
    hipMemsetAsync(cursor, 0, NNODES * sizeof(int), stream);
    fill_kernel<<<(NEDGES + 255) / 256, 256, 0, stream>>>(src, dst, offsets, cursor,
                                                          csr_src, NEDGES);
    pack_xx_kernel<<<(ROWS * K0PAD + 255) / 256, 256, 0, stream>>>(xx, xx16);
    packWt_kernel<<<dim3(256, 4), 256, 0, stream>>>(W[0], W[1], W[2], W[3],
                                                    (unsigned short*)Wt0,
                                                    (unsigned short*)Wt1,
                                                    (unsigned short*)Wt2,
                                                    (unsigned short*)Wt3);

    for (int t = 0; t < NT; ++t) {
        for (int l = 0; l < 4; ++l) {
            const unsigned short* A16 = (l == 0) ? xx16 : act16;
            int K = (l == 0) ? K0PAD : NHD;
            int apply_bn = (l > 0) ? 1 : 0;
            gemm_mfma_kernel<<<ROWS / BM, 256, 0, stream>>>(A16, Wt[l], al[l], ar[l],
                                                            bnss, apply_bn,
                                                            h16, el, er, K);
            attn_kernel<<<ROWS / 4, 256, 0, stream>>>(h16, el, er, offsets, csr_src,
                                                      act16, sums);
            // finalize layer-l stats -> bnss (scale/shift), re-zero sums
            bnfinal_kernel<<<1, 256, 0, stream>>>(sums, gamma[l], beta[l], bnss);
        }
        headout_kernel<<<ROWS / 4, 256, 0, stream>>>(act16, bnss, W_out, b_out,
                                                     out, xx16, t);
    }
}

// Round 14
// 1321.740 us; speedup vs baseline: 1.1554x; 1.0109x over previous
//
#include <hip/hip_runtime.h>
#include <math.h>

#define NNODES 5000
#define NEDGES 80000
#define NB 8
#define NIN 30
#define K0PAD 32
#define NH 4
#define ND 64
#define NHD 256
#define NT 5
#define NOUT 3
#define ROWS (NB * NNODES) // 40000
#define BNEPS 1e-5f
#define KP 40   // LDS k-stride for A tile (shorts)
#define NREP 64 // sums[] replicas
#define BM 32   // gemm M-tile
#define CSTR 264 // epilogue C-stage row stride (shorts); 264 -> 4-lane bank alias

#define GLOBAL_AS __attribute__((address_space(1)))
#define LDS_AS __attribute__((address_space(3)))

typedef short shortx8 __attribute__((ext_vector_type(8)));
typedef _Float16 halfx8 __attribute__((ext_vector_type(8)));
typedef _Float16 halfx4 __attribute__((ext_vector_type(4)));
typedef _Float16 halfx2 __attribute__((ext_vector_type(2)));
typedef float floatx4 __attribute__((ext_vector_type(4)));
typedef int intx4 __attribute__((ext_vector_type(4)));

static __device__ __forceinline__ unsigned short f2h(float f) {
    union { _Float16 h; unsigned short u; } v;
    v.h = (_Float16)f;
    return v.u;
}
static __device__ __forceinline__ float h2f(unsigned short u) {
    union { _Float16 h; unsigned short u; } v;
    v.u = u;
    return (float)v.h;
}
static __device__ __forceinline__ halfx8 splat8(_Float16 x) {
    return (halfx8){x, x, x, x, x, x, x, x};
}

// ---------------- CSR build ----------------

__global__ void count_kernel(const int* __restrict__ dst, int* __restrict__ counts, int n) {
    int e = blockIdx.x * blockDim.x + threadIdx.x;
    if (e < n) atomicAdd(&counts[dst[e]], 1);
}

__global__ __launch_bounds__(1024) void scan_kernel(const int* __restrict__ counts,
                                                    int* __restrict__ offsets, int n) {
    __shared__ int smem[1024];
    const int CH = 5;
    int tid = threadIdx.x;
    int base = tid * CH;
    int loc[CH];
    int s = 0;
    for (int j = 0; j < CH; ++j) {
        int i = base + j;
        int v = (i < n) ? counts[i] : 0;
        loc[j] = s;
        s += v;
    }
    smem[tid] = s;
    __syncthreads();
    for (int off = 1; off < 1024; off <<= 1) {
        int v = (tid >= off) ? smem[tid - off] : 0;
        __syncthreads();
        smem[tid] += v;
        __syncthreads();
    }
    int excl = smem[tid] - s;
    for (int j = 0; j < CH; ++j) {
        int i = base + j;
        if (i < n) offsets[i] = excl + loc[j];
    }
    if (tid == 1023) offsets[n] = smem[1023];
}

__global__ void fill_kernel(const int* __restrict__ src, const int* __restrict__ dst,
                            const int* __restrict__ offsets, int* __restrict__ cursor,
                            int* __restrict__ csr_src, int n) {
    int e = blockIdx.x * blockDim.x + threadIdx.x;
    if (e >= n) return;
    int d = dst[e];
    int pos = offsets[d] + atomicAdd(&cursor[d], 1);
    csr_src[pos] = src[e];
}

// ---------------- packing ----------------

__global__ void pack_xx_kernel(const float* __restrict__ xx, unsigned short* __restrict__ xx16) {
    int idx = blockIdx.x * blockDim.x + threadIdx.x;
    if (idx >= ROWS * K0PAD) return;
    int g = idx >> 5;
    int k = idx & 31;
    float v = (k < NIN) ? xx[(size_t)g * NIN + k] : 0.0f;
    xx16[idx] = f2h(v);
}

// WtP: per 32-k tile, 16B chunks (n,quad) at swizzled pos p = n*4 + (quad ^ ((n>>1)&3)).
__global__ void packWt_kernel(const float* __restrict__ W0, const float* __restrict__ W1,
                              const float* __restrict__ W2, const float* __restrict__ W3,
                              unsigned short* __restrict__ P0, unsigned short* __restrict__ P1,
                              unsigned short* __restrict__ P2, unsigned short* __restrict__ P3) {
    int l = blockIdx.y;
    const float* W = (l == 0) ? W0 : (l == 1) ? W1 : (l == 2) ? W2 : W3;
    unsigned short* WtP = (l == 0) ? P0 : (l == 1) ? P1 : (l == 2) ? P2 : P3;
    int Kin = (l == 0) ? NIN : NHD;
    int Kpad = (l == 0) ? K0PAD : NHD;
    int n = blockIdx.x;
    int k = threadIdx.x;
    if (k < Kpad) {
        float v = (k < Kin) ? W[(size_t)k * NHD + n] : 0.0f;
        int t = k >> 5;
        int quad = (k >> 3) & 3;
        int j = k & 7;
        int p = n * 4 + (quad ^ ((n >> 1) & 3));
        WtP[(size_t)t * (NHD * 32) + p * 8 + j] = f2h(v);
    }
}

// ---------------- BN finalize: 64 replicas -> scale/shift table (once) ----------------

__global__ __launch_bounds__(256) void bnfinal_kernel(float* __restrict__ sums,
                                                      const float* __restrict__ gamma,
                                                      const float* __restrict__ beta,
                                                      float* __restrict__ bnss) {
    int c = threadIdx.x;
    float s = 0.0f, s2 = 0.0f;
#pragma unroll
    for (int r = 0; r < NREP; ++r) {
        s += sums[r * 2 * NHD + c];
        s2 += sums[r * 2 * NHD + NHD + c];
        sums[r * 2 * NHD + c] = 0.0f;
        sums[r * 2 * NHD + NHD + c] = 0.0f;
    }
    const float invn = 1.0f / (float)ROWS;
    float mu = s * invn;
    float var = s2 * invn - mu * mu;
    float sc = rsqrtf(var + BNEPS) * gamma[c];
    bnss[c] = sc;
    bnss[NHD + c] = beta[c] - mu * sc;
}

// ---------------- MFMA GEMM + fused BN(prev layer, packed f16) + fused el/er ----------------
// B tile via global_load_lds 16B DMA; A staging BN+lrelu with v_pk_fma_f16;
// epilogue stages C through LDS for coalesced 16B stores.

__global__ __launch_bounds__(256) void gemm_mfma_kernel(
    const unsigned short* __restrict__ A, const unsigned short* __restrict__ Wt,
    const float* __restrict__ alw, const float* __restrict__ arw,
    const float* __restrict__ bnss, int apply_bn,
    unsigned short* __restrict__ C16, float* __restrict__ el, float* __restrict__ er,
    int K) {
    __shared__ __align__(16) short smem_s[BM * KP + NHD * 32]; // As | Bs, reused as Cs
    __shared__ __align__(16) unsigned short bnsc16[NHD];
    __shared__ __align__(16) unsigned short bnsh16[NHD];
    short* As = smem_s;
    short* Bs = smem_s + BM * KP;
    int tid = threadIdx.x;
    if (apply_bn) {
        bnsc16[tid] = f2h(bnss[tid]);
        bnsh16[tid] = f2h(bnss[NHD + tid]);
    }
    __syncthreads();

    int wave = tid >> 6; // head
    int lane = tid & 63;
    int c = lane & 15;
    int quad = lane >> 4;
    int xorv = (c >> 1) & 3;
    int row0 = blockIdx.x * BM;

    floatx4 acc[2][4];
#pragma unroll
    for (int mt = 0; mt < 2; ++mt)
#pragma unroll
        for (int nt = 0; nt < 4; ++nt) acc[mt][nt] = (floatx4){0.f, 0.f, 0.f, 0.f};

    int r = tid >> 2;   // 0..63 (only <BM used)
    int seg = tid & 3;
    const halfx8 p01 = splat8((_Float16)0.01f);
    for (int k0 = 0; k0 < K; k0 += 32) {
        const unsigned short* gB = Wt + (size_t)(k0 >> 5) * (NHD * 32);
#pragma unroll
        for (int i = 0; i < 4; ++i) {
            int ci = i * 256 + tid;
            __builtin_amdgcn_global_load_lds(
                (const GLOBAL_AS unsigned int*)(gB + ci * 8),
                (LDS_AS unsigned int*)(&Bs[ci * 8]), 16, 0, 0);
        }
        if (r < BM) {
            shortx8 v = *(const shortx8*)(A + (size_t)(row0 + r) * K + k0 + seg * 8);
            if (apply_bn) {
                halfx8 hv = *(halfx8*)&v;
                int kg = k0 + seg * 8;
                halfx8 sc = *(const halfx8*)(&bnsc16[kg]);
                halfx8 sh = *(const halfx8*)(&bnsh16[kg]);
                halfx8 x = hv * sc + sh;             // v_pk_fma_f16
                hv = __builtin_elementwise_max(x, x * p01); // leaky relu, packed
                v = *(shortx8*)&hv;
            }
            *(shortx8*)(&As[r * KP + seg * 8]) = v;
        }
        __syncthreads();
        halfx8 a[2], b[4];
#pragma unroll
        for (int mt = 0; mt < 2; ++mt)
            a[mt] = *(const halfx8*)(&As[(mt * 16 + c) * KP + quad * 8]);
#pragma unroll
        for (int nt = 0; nt < 4; ++nt) {
            int pq = (wave * 64 + nt * 16 + c) * 4 + (quad ^ xorv);
            b[nt] = *(const halfx8*)(&Bs[pq * 8]);
        }
#pragma unroll
        for (int mt = 0; mt < 2; ++mt)
#pragma unroll
            for (int nt = 0; nt < 4; ++nt)
                acc[mt][nt] = __builtin_amdgcn_mfma_f32_16x16x32_f16(a[mt], b[nt],
                                                                     acc[mt][nt], 0, 0, 0);
        __syncthreads();
    }

    // epilogue: stage f16 C in LDS (reuse smem), fused el/er from fp32 acc
    short* Cs = smem_s; // stride CSTR shorts per row; 32*CSTR <= BM*KP+NHD*32
    float alv[4], arv[4];
#pragma unroll
    for (int nt = 0; nt < 4; ++nt) {
        alv[nt] = alw[wave * 64 + nt * 16 + c];
        arv[nt] = arw[wave * 64 + nt * 16 + c];
    }
#pragma unroll
    for (int mt = 0; mt < 2; ++mt) {
#pragma unroll
        for (int rr = 0; rr < 4; ++rr) {
            int rl = mt * 16 + quad * 4 + rr;
            int row = row0 + rl;
            float pl = 0.0f, pr = 0.0f;
#pragma unroll
            for (int nt = 0; nt < 4; ++nt) {
                float v = acc[mt][nt][rr];
                Cs[rl * CSTR + wave * 64 + nt * 16 + c] = (short)f2h(v);
                pl += v * alv[nt];
                pr += v * arv[nt];
            }
#pragma unroll
            for (int o = 1; o < 16; o <<= 1) {
                pl += __shfl_xor(pl, o);
                pr += __shfl_xor(pr, o);
            }
            if (c == mt * 4 + rr) {
                el[(size_t)row * NH + wave] = pl;
                er[(size_t)row * NH + wave] = pr;
            }
        }
    }
    __syncthreads();
#pragma unroll
    for (int i = 0; i < 4; ++i) {
        int rl = i * 8 + (tid >> 5);
        int col = (tid & 31) * 8;
        shortx8 vv = *(const shortx8*)(&Cs[rl * CSTR + col]);
        *(shortx8*)(&C16[(size_t)(row0 + rl) * NHD + col]) = vv;
    }
}

// ---------------- edge softmax + aggregate (packed-f16 gather) + BN partials ----------------
// Wave per node. Phase 1 fp32 logits once per node. Phase 2: weights pre-scaled
// by 1/sm (convex combo -> bounded f16 acc), halfx8 loads, v_pk_fma_f16.

__global__ __launch_bounds__(256) void attn_kernel(const unsigned short* __restrict__ h16,
                                                   const float* __restrict__ el,
                                                   const float* __restrict__ er,
                                                   const int* __restrict__ offsets,
                                                   const int* __restrict__ csr_src,
                                                   unsigned short* __restrict__ out16,
                                                   float* __restrict__ sums_cur) {
    __shared__ float bnpart[4][2][NHD]; // 8 KB
    int p = blockIdx.x;
    int tid = threadIdx.x;
    int b = p & 7;
    int wave = tid >> 6;
    int lane = tid & 63;
    int head = lane >> 4;
    int li = lane & 15;
    int n = ((p >> 3) << 2) + wave;
    int g = b * NNODES + n;
    int start = offsets[n];
    int deg = offsets[n + 1] - start;
    const float* elb = el + (size_t)b * NNODES * NH;
    float er_nh = er[(size_t)g * NH + head];
    float* bw = &bnpart[wave][0][0];

    if (deg == 0) {
        *(unsigned long long*)(out16 + (size_t)g * NHD + lane * 4) = 0ULL;
        int c4 = lane * 4;
#pragma unroll
        for (int j = 0; j < 4; ++j) {
            bw[c4 + j] = 0.0f;
            bw[NHD + c4 + j] = 0.0f;
        }
    } else if (deg <= 64) {
        // phase 1 (fp32): lane li of each head-group owns edges li+16k
        float e[4], w[4];
        int s[4];
#pragma unroll
        for (int k = 0; k < 4; ++k) {
            int idx = k * 16 + li;
            if (idx < deg) {
                s[k] = csr_src[start + idx];
                float t = elb[s[k] * NH + head] + er_nh;
                e[k] = (t > 0.0f) ? t : 0.2f * t;
            } else {
                s[k] = 0;
                e[k] = -INFINITY;
            }
        }
        float mx = fmaxf(fmaxf(e[0], e[1]), fmaxf(e[2], e[3]));
#pragma unroll
        for (int o = 8; o; o >>= 1) mx = fmaxf(mx, __shfl_xor(mx, o));
        float sm = 0.0f;
#pragma unroll
        for (int k = 0; k < 4; ++k) {
            w[k] = __expf(e[k] - mx);
            sm += w[k];
        }
#pragma unroll
        for (int o = 8; o; o >>= 1) sm += __shfl_xor(sm, o);

        // phase 2: packed f16, weights pre-normalized by 1/sm of the CHANNEL head
        int sub = lane >> 5;
        int i32 = lane & 31;
        int hsel = (lane & 24) << 1;  // channel head (i32>>3) * 16
        float smh = __shfl(sm, hsel);
        float invsm = 1.0f / smh;
        const unsigned short* hrow = h16 + (size_t)b * NNODES * NHD + i32 * 8;
        halfx8 acc = splat8((_Float16)0.0f);
#define GATHER_CHUNK(K)                                                          \
        if (deg > (K) * 16) {                                                    \
            int cnt = deg - (K) * 16;                                            \
            cnt = (cnt > 16) ? 16 : cnt;                                         \
            int j = 0;                                                           \
            for (; j + 4 <= cnt; j += 4) {                                       \
                int sa = __shfl(s[K], j + sub);                                  \
                float wa = __shfl(w[K], hsel + j + sub);                         \
                int sb = __shfl(s[K], j + 2 + sub);                              \
                float wb = __shfl(w[K], hsel + j + 2 + sub);                     \
                halfx8 ha = *(const halfx8*)(hrow + (size_t)sa * NHD);           \
                halfx8 hb = *(const halfx8*)(hrow + (size_t)sb * NHD);           \
                acc += ha * splat8((_Float16)(wa * invsm));                      \
                acc += hb * splat8((_Float16)(wb * invsm));                      \
            }                                                                    \
            for (; j < cnt; j += 2) {                                            \
                int e2 = j + sub;                                                \
                bool valid = (e2 < cnt);                                         \
                int ec = valid ? e2 : (cnt - 1);                                 \
                int sa = __shfl(s[K], ec);                                       \
                float wa0 = __shfl(w[K], hsel + ec);                             \
                float wa = valid ? wa0 * invsm : 0.0f;                           \
                halfx8 ha = *(const halfx8*)(hrow + (size_t)sa * NHD);           \
                acc += ha * splat8((_Float16)wa);                                \
            }                                                                    \
        }
        GATHER_CHUNK(0)
        GATHER_CHUNK(1)
        GATHER_CHUNK(2)
        GATHER_CHUNK(3)
#undef GATHER_CHUNK
        // combine the two edge-subgroups (lane ^ 32), packed add
        intx4 ai = *(intx4*)&acc;
        intx4 bi;
        bi[0] = __shfl_xor(ai[0], 32);
        bi[1] = __shfl_xor(ai[1], 32);
        bi[2] = __shfl_xor(ai[2], 32);
        bi[3] = __shfl_xor(ai[3], 32);
        acc += *(halfx8*)&bi;
        if (sub == 0) {
            *(halfx8*)(out16 + (size_t)g * NHD + i32 * 8) = acc;
            int c8 = i32 * 8;
#pragma unroll
            for (int j = 0; j < 8; ++j) {
                float v = (float)acc[j];
                bw[c8 + j] = v;
                bw[NHD + c8 + j] = v * v;
            }
        }
    } else {
        // generic fallback (deg > 64, rare) — fp32 path
        const unsigned short* hbase = h16 + (size_t)b * NNODES * NHD + lane * 4;
        float mx = -INFINITY;
        for (int i = li; i < deg; i += 16) {
            int s2 = csr_src[start + i];
            float t = elb[s2 * NH + head] + er_nh;
            t = (t > 0.0f) ? t : 0.2f * t;
            mx = fmaxf(mx, t);
        }
#pragma unroll
        for (int o = 8; o; o >>= 1) mx = fmaxf(mx, __shfl_xor(mx, o));
        float sm = 0.0f;
        for (int i = li; i < deg; i += 16) {
            int s2 = csr_src[start + i];
            float t = elb[s2 * NH + head] + er_nh;
            t = (t > 0.0f) ? t : 0.2f * t;
            sm += __expf(t - mx);
        }
#pragma unroll
        for (int o = 8; o; o >>= 1) sm += __shfl_xor(sm, o);
        float a0 = 0.f, a1 = 0.f, a2 = 0.f, a3 = 0.f;
        for (int j = 0; j < deg; ++j) {
            int s2 = csr_src[start + j];
            float t = elb[s2 * NH + head] + er_nh;
            t = (t > 0.0f) ? t : 0.2f * t;
            float wj = __expf(t - mx);
            halfx4 hv = *(const halfx4*)(hbase + (size_t)s2 * NHD);
            a0 += wj * (float)hv[0];
            a1 += wj * (float)hv[1];
            a2 += wj * (float)hv[2];
            a3 += wj * (float)hv[3];
        }
        float inv = 1.0f / sm;
        halfx4 o4;
        o4[0] = (_Float16)(a0 * inv);
        o4[1] = (_Float16)(a1 * inv);
        o4[2] = (_Float16)(a2 * inv);
        o4[3] = (_Float16)(a3 * inv);
        *(halfx4*)(out16 + (size_t)g * NHD + lane * 4) = o4;
        int c4 = lane * 4;
#pragma unroll
        for (int j = 0; j < 4; ++j) {
            float v = (float)o4[j];
            bw[c4 + j] = v;
            bw[NHD + c4 + j] = v * v;
        }
    }
    __syncthreads();
    {
        int c = tid;
        float s = bnpart[0][0][c] + bnpart[1][0][c] + bnpart[2][0][c] + bnpart[3][0][c];
        float s2 = bnpart[0][1][c] + bnpart[1][1][c] + bnpart[2][1][c] + bnpart[3][1][c];
        float* sr = sums_cur + (p & (NREP - 1)) * 2 * NHD;
        atomicAdd(&sr[c], s);
        atomicAdd(&sr[NHD + c], s2);
    }
}

// ---------------- output head (BN table from bnss) + f16 window shift ----------------

__global__ __launch_bounds__(256) void headout_kernel(const unsigned short* __restrict__ x16,
                                                      const float* __restrict__ bnss,
                                                      const float* __restrict__ Wout,
                                                      const float* __restrict__ bout,
                                                      float* __restrict__ out,
                                                      unsigned short* __restrict__ xx16, int t) {
    __shared__ float bsc[NHD];
    __shared__ float bsh[NHD];
    {
        int c = threadIdx.x;
        bsc[c] = bnss[c];
        bsh[c] = bnss[NHD + c];
    }
    __syncthreads();

    int wave = threadIdx.x >> 6;
    int lane = threadIdx.x & 63;
    int g = blockIdx.x * 4 + wave;
    int c0 = lane * 4;
    halfx4 hv = *(const halfx4*)(x16 + (size_t)g * NHD + c0);
    float vv[4];
#pragma unroll
    for (int j = 0; j < 4; ++j) {
        float x = fmaf((float)hv[j], bsc[c0 + j], bsh[c0 + j]);
        vv[j] = (x > 0.0f) ? x : 0.01f * x;
    }
    float r0 = vv[0] * Wout[(c0 + 0) * NOUT + 0] + vv[1] * Wout[(c0 + 1) * NOUT + 0] +
               vv[2] * Wout[(c0 + 2) * NOUT + 0] + vv[3] * Wout[(c0 + 3) * NOUT + 0];
    float r1 = vv[0] * Wout[(c0 + 0) * NOUT + 1] + vv[1] * Wout[(c0 + 1) * NOUT + 1] +
               vv[2] * Wout[(c0 + 2) * NOUT + 1] + vv[3] * Wout[(c0 + 3) * NOUT + 1];
    float r2 = vv[0] * Wout[(c0 + 0) * NOUT + 2] + vv[1] * Wout[(c0 + 1) * NOUT + 2] +
               vv[2] * Wout[(c0 + 2) * NOUT + 2] + vv[3] * Wout[(c0 + 3) * NOUT + 2];
#pragma unroll
    for (int o = 32; o; o >>= 1) {
        r0 += __shfl_xor(r0, o);
        r1 += __shfl_xor(r1, o);
        r2 += __shfl_xor(r2, o);
    }
    float o0 = r0 + bout[0], o1 = r1 + bout[1], o2 = r2 + bout[2];
    if (lane == 0) {
        float* op = out + ((size_t)g * NT + t) * NOUT;
        op[0] = o0;
        op[1] = o1;
        op[2] = o2;
    }
    float oldv = (lane < NIN) ? h2f(xx16[(size_t)g * K0PAD + lane]) : 0.0f;
    float shifted = __shfl(oldv, lane + 3);
    float newv = (lane < 27) ? shifted : (lane == 27 ? o0 : (lane == 28 ? o1 : o2));
    if (lane < NIN) xx16[(size_t)g * K0PAD + lane] = f2h(newv);
}

// ---------------- launch ----------------

extern "C" void kernel_launch(void* const* d_in, const int* in_sizes, int n_in,
                              void* d_out, int out_size, void* d_ws, size_t ws_size,
                              hipStream_t stream) {
    const float* xx = (const float*)d_in[0];
    const int* src = (const int*)d_in[1];
    const int* dst = (const int*)d_in[2];
    const float* W[4] = {(const float*)d_in[3], (const float*)d_in[8],
                         (const float*)d_in[13], (const float*)d_in[18]};
    const float* al[4] = {(const float*)d_in[4], (const float*)d_in[9],
                          (const float*)d_in[14], (const float*)d_in[19]};
    const float* ar[4] = {(const float*)d_in[5], (const float*)d_in[10],
                          (const float*)d_in[15], (const float*)d_in[20]};
    const float* gamma[4] = {(const float*)d_in[6], (const float*)d_in[11],
                             (const float*)d_in[16], (const float*)d_in[21]};
    const float* beta[4] = {(const float*)d_in[7], (const float*)d_in[12],
                            (const float*)d_in[17], (const float*)d_in[22]};
    const float* W_out = (const float*)d_in[23];
    const float* b_out = (const float*)d_in[24];
    float* out = (float*)d_out;

    // workspace carve
    float* wsf = (float*)d_ws;
    float* el = wsf;                                        // ROWS*NH
    float* er = el + (size_t)ROWS * NH;                     // ROWS*NH
    float* sums = er + (size_t)ROWS * NH;                   // NREP*2*NHD
    float* bnss = sums + NREP * 2 * NHD;                    // 2*NHD (scale|shift)
    unsigned short* h16 = (unsigned short*)(bnss + 2 * NHD); // ROWS*NHD
    unsigned short* act16 = h16 + (size_t)ROWS * NHD;       // ROWS*NHD (attn out)
    unsigned short* xx16 = act16 + (size_t)ROWS * NHD;      // ROWS*K0PAD
    unsigned short* Wt0 = xx16 + (size_t)ROWS * K0PAD;      // 256*K0PAD
    unsigned short* Wt1 = Wt0 + 256 * K0PAD;                // 256*256
    unsigned short* Wt2 = Wt1 + 256 * NHD;
    unsigned short* Wt3 = Wt2 + 256 * NHD;
    int* counts = (int*)(Wt3 + 256 * NHD);                  // NNODES
    int* offsets = counts + NNODES;                         // NNODES+1 (+pad)
    int* cursor = offsets + NNODES + 8;                     // NNODES
    int* csr_src = cursor + NNODES;                         // NEDGES
    const unsigned short* Wt[4] = {Wt0, Wt1, Wt2, Wt3};

    // ---- CSR build + packing (once per launch) ----
    hipMemsetAsync(counts, 0, NNODES * sizeof(int), stream);
    hipMemsetAsync(sums, 0, NREP * 2 * NHD * sizeof(float), stream);
    count_kernel<<<(NEDGES + 255) / 256, 256, 0, stream>>>(dst, counts, NEDGES);
    scan_kernel<<<1, 1024, 0, stream>>>(counts, offsets, NNODES);
    hipMemsetAsync(cursor, 0, NNODES * sizeof(int), stream);
    fill_kernel<<<(NEDGES + 255) / 256, 256, 0, stream>>>(src, dst, offsets, cursor,
                                                          csr_src, NEDGES);
    pack_xx_kernel<<<(ROWS * K0PAD + 255) / 256, 256, 0, stream>>>(xx, xx16);
    packWt_kernel<<<dim3(256, 4), 256, 0, stream>>>(W[0], W[1], W[2], W[3],
                                                    (unsigned short*)Wt0,
                                                    (unsigned short*)Wt1,
                                                    (unsigned short*)Wt2,
                                                    (unsigned short*)Wt3);

    for (int t = 0; t < NT; ++t) {
        for (int l = 0; l < 4; ++l) {
            const unsigned short* A16 = (l == 0) ? xx16 : act16;
            int K = (l == 0) ? K0PAD : NHD;
            int apply_bn = (l > 0) ? 1 : 0;
            gemm_mfma_kernel<<<ROWS / BM, 256, 0, stream>>>(A16, Wt[l], al[l], ar[l],
                                                            bnss, apply_bn,
                                                            h16, el, er, K);
            attn_kernel<<<ROWS / 4, 256, 0, stream>>>(h16, el, er, offsets, csr_src,
                                                      act16, sums);
            bnfinal_kernel<<<1, 256, 0, stream>>>(sums, gamma[l], beta[l], bnss);
        }
        headout_kernel<<<ROWS / 4, 256, 0, stream>>>(act16, bnss, W_out, b_out,
                                                     out, xx16, t);
    }
}